// Round 9
// baseline (120.251 us; speedup 1.0000x reference)
//
#include <hip/hip_runtime.h>

#define BATCH 16
#define C_IN  64
#define HH    64
#define WW    64
#define COUT  64
#define KK    9
#define HW    4096
#define CK    576
#define MROW  200   // 192 data ushorts + 8 pad; row stride 400 B (16-B aligned)

typedef __bf16 bf16x8 __attribute__((ext_vector_type(8)));
typedef float  f32x4  __attribute__((ext_vector_type(4)));
typedef unsigned int u32x2 __attribute__((ext_vector_type(2)));  // NT-loadable

__device__ __forceinline__ unsigned int f32_to_bf16_rne(float f) {
    unsigned int b = __float_as_uint(f);
    b += 0x7FFFu + ((b >> 16) & 1u);
    return b >> 16;  // low 16 bits valid
}

// Fused prep.  Blocks 0..1023: x (B,C,H,W) f32 -> xt (B,H,W,C) bf16.
// Blocks 1024..1167: w (Cout,C,3,3) f32 -> wt in MFMA A-fragment order:
//   wt[(((kc*6+ks)*4+ot)*64 + lane)*8 + j] = W[o=ot*16+(lane&15)]
//        [kk=ks*32+(lane>>4)*8+j] of chunk kc  (kk = tap*64+c, k=kc*3+tap)
__global__ __launch_bounds__(256) void prep_kernel(
    const float* __restrict__ x, const float* __restrict__ w,
    unsigned short* __restrict__ xt, unsigned short* __restrict__ wt) {
    __shared__ unsigned short tile[64][72];
    const int t = threadIdx.x;
    const int blk = blockIdx.x;
    if (blk < 1024) {
        const int b = blk >> 6, y = blk & 63;
        const float* xrow = x + ((b * 64) * 64 + y) * 64;
#pragma unroll
        for (int it = 0; it < 4; ++it) {
            const int idx = it * 256 + t;
            const int c = idx >> 4, seg = idx & 15;
            const float4 v = *(const float4*)(xrow + c * HW + seg * 4);
            tile[seg * 4 + 0][c] = (unsigned short)f32_to_bf16_rne(v.x);
            tile[seg * 4 + 1][c] = (unsigned short)f32_to_bf16_rne(v.y);
            tile[seg * 4 + 2][c] = (unsigned short)f32_to_bf16_rne(v.z);
            tile[seg * 4 + 3][c] = (unsigned short)f32_to_bf16_rne(v.w);
        }
        __syncthreads();
#pragma unroll
        for (int it = 0; it < 2; ++it) {
            const int idx = it * 256 + t;
            const int xx = idx >> 3, cs = idx & 7;
            *(int4*)&xt[((b * HW) + y * 64 + xx) * 64 + cs * 8] =
                *(const int4*)&tile[xx][cs * 8];
        }
    } else {
        const int i = (blk - 1024) * 256 + t;  // 0..36863
        const int j = i & 7;
        const int l = (i >> 3) & 63;
        const int ot = (i >> 9) & 3;
        const int r = i >> 11;           // 0..17
        const int ks = r % 6, kc = r / 6;
        const int o  = ot * 16 + (l & 15);
        const int kk = ks * 32 + (l >> 4) * 8 + j;
        const int tap = kk >> 6, c = kk & 63;
        const int k = kc * 3 + tap;
        wt[i] = (unsigned short)f32_to_bf16_rne(w[o * CK + c * KK + k]);
    }
}

// Main.  Block = 128 thr = 2 waves; wave owns a 16-px strip x 64 cout,
// wave-private LDS, no __syncthreads.
// R8/R9 change (theory: L1 thrash on the wt stream): the scattered xt
// gathers (~300 KB/CU) and one-touch offset/mask loads are NON-TEMPORAL so
// they stop evicting wt (24 KB per chunk) from the 32 KB L1.  wt afrag
// loads (1.15 MB/CU, wave-uniform) then become L1 broadcast hits instead of
// ~200-cyc L2 round-trips — R7's dominant stall.  (R9 = R8 with the
// nontemporal builtin fed native ext_vector types; HIP uint2 is rejected.)
// Retained: CU-clustered strip map (R7), XCD image pinning (R2),
// prologue-hoisted params (R7), 48-deep pinned gather batches (R7).
__global__ __launch_bounds__(128, 3) void dcn_main_kernel(
    const float* __restrict__ offset, const float* __restrict__ mask,
    const unsigned short* __restrict__ xt, const unsigned short* __restrict__ wt,
    const float* __restrict__ bias, float* __restrict__ out) {
    __shared__ __align__(16) unsigned short Mlds[2][16 * MROW];  // 12800 B
    __shared__ __align__(16) int PWw[2][144 * 4];                //  4608 B
    __shared__ __align__(8) unsigned short PWa[2][144 * 4];      //  2304 B

    const int t    = threadIdx.x;
    const int wave = __builtin_amdgcn_readfirstlane(t >> 6);
    const int lane = t & 63;
    const int quad = lane >> 4, m16 = lane & 15;

    const int blk = blockIdx.x;
    const int xcd = blk & 7;                    // L2 image pinning (R2 win)
    const int i8  = blk >> 3;                   // 0..255 within XCD
    const int s   = ((i8 & 31) << 3) | (i8 >> 5);  // CU-clustered strip id
    const int b   = (xcd << 1) | (s >> 7);
    const int rr  = s & 127;
    const int row = rr >> 1;
    const int qbase = (rr & 1) * 32 + wave * 16;

    f32x4 acc[4];
#pragma unroll
    for (int ot = 0; ot < 4; ++ot)
#pragma unroll
        for (int r = 0; r < 4; ++r) acc[ot][r] = 0.f;

    const float* offb = offset + b * (2 * KK * HW) + row * 64;
    const float* mb   = mask + b * (KK * HW) + row * 64;
    const char* xtb   = (const char*)(xt + b * (HW * 64));
    char* MW = (char*)Mlds[wave];
    const int co = m16 * 8;          // channel byte offset within a pixel

    // ---- Prologue: params for all 9 taps x 16 px -> PWw/PWa ----
#pragma unroll
    for (int p = 0; p < 3; ++p) {
        if (lane < 48) {
            const int t3  = lane >> 4;          // kx
            const int tap = p * 3 + t3;         // global tap; ky = p
            const int pxi = lane & 15;
            const int q = qbase + pxi;
            const float oy = __builtin_nontemporal_load(&offb[(2 * tap) * HW + q]);
            const float ox = __builtin_nontemporal_load(&offb[(2 * tap + 1) * HW + q]);
            const float mk = __builtin_nontemporal_load(&mb[tap * HW + q]);
            const float py  = oy + (float)(row - 1 + p);
            const float pxf = ox + (float)(q - 1 + t3);
            const float y0f = floorf(py), x0f = floorf(pxf);
            const float wy = py - y0f, wx = pxf - x0f;
            const int y0 = (int)y0f, x0 = (int)x0f;
            const int y1 = y0 + 1,   x1 = x0 + 1;
            const float vy0 = (y0 >= 0 && y0 < HH) ? 1.f : 0.f;
            const float vy1 = (y1 >= 0 && y1 < HH) ? 1.f : 0.f;
            const float vx0 = (x0 >= 0 && x0 < WW) ? 1.f : 0.f;
            const float vx1 = (x1 >= 0 && x1 < WW) ? 1.f : 0.f;
            const float w00 = (1.f - wy) * (1.f - wx) * vy0 * vx0 * mk;
            const float w01 = (1.f - wy) * wx         * vy0 * vx1 * mk;
            const float w10 = wy * (1.f - wx)         * vy1 * vx0 * mk;
            const float w11 = wy * wx                 * vy1 * vx1 * mk;
            const int cy0 = min(max(y0, 0), HH - 1), cy1 = min(max(y1, 0), HH - 1);
            const int cx0 = min(max(x0, 0), WW - 1), cx1 = min(max(x1, 0), WW - 1);
            const int it = tap * 16 + pxi;
            int4 P0;
            P0.x = __float_as_int(w00); P0.y = __float_as_int(w01);
            P0.z = __float_as_int(w10); P0.w = __float_as_int(w11);
            *(int4*)&PWw[wave][it * 4] = P0;
            ushort4 A;
            A.x = (unsigned short)(cy0 * 64 + cx0);
            A.y = (unsigned short)(cy0 * 64 + cx1);
            A.z = (unsigned short)(cy1 * 64 + cx0);
            A.w = (unsigned short)(cy1 * 64 + cx1);
            *(ushort4*)&PWa[wave][it * 4] = A;
        }
    }

    u32x2 g[12][4];                  // 48 in-flight NT gathers (96 VGPR)

    auto bload = [&](int kc) {
        const unsigned short* Pa = &PWa[wave][0] + 48 * kc * 4;
#pragma unroll
        for (int i = 0; i < 12; ++i) {
            const int l = i * 4 + quad;
            const ushort4 a = *(const ushort4*)(Pa + l * 4);
            g[i][0] = __builtin_nontemporal_load(
                (const u32x2*)(xtb + ((int)a.x << 7) + co));
            g[i][1] = __builtin_nontemporal_load(
                (const u32x2*)(xtb + ((int)a.y << 7) + co));
            g[i][2] = __builtin_nontemporal_load(
                (const u32x2*)(xtb + ((int)a.z << 7) + co));
            g[i][3] = __builtin_nontemporal_load(
                (const u32x2*)(xtb + ((int)a.w << 7) + co));
        }
    };

    auto bfinish = [&](int kc) {
        const int* Pw = &PWw[wave][0] + 48 * kc * 4;
#pragma unroll
        for (int i = 0; i < 12; ++i) {
            const int l = i * 4 + quad;
            const int4 p0 = *(const int4*)(Pw + l * 4);
            const float fw00 = __int_as_float(p0.x), fw01 = __int_as_float(p0.y);
            const float fw10 = __int_as_float(p0.z), fw11 = __int_as_float(p0.w);
            const u32x2 u0 = g[i][0], u1 = g[i][1], u2 = g[i][2], u3 = g[i][3];
            float v0, v1, v2, v3;
            v0 = fw00 * __uint_as_float(u0.x << 16);
            v1 = fw00 * __uint_as_float(u0.x & 0xFFFF0000u);
            v2 = fw00 * __uint_as_float(u0.y << 16);
            v3 = fw00 * __uint_as_float(u0.y & 0xFFFF0000u);
            v0 = fmaf(fw01, __uint_as_float(u1.x << 16), v0);
            v1 = fmaf(fw01, __uint_as_float(u1.x & 0xFFFF0000u), v1);
            v2 = fmaf(fw01, __uint_as_float(u1.y << 16), v2);
            v3 = fmaf(fw01, __uint_as_float(u1.y & 0xFFFF0000u), v3);
            v0 = fmaf(fw10, __uint_as_float(u2.x << 16), v0);
            v1 = fmaf(fw10, __uint_as_float(u2.x & 0xFFFF0000u), v1);
            v2 = fmaf(fw10, __uint_as_float(u2.y << 16), v2);
            v3 = fmaf(fw10, __uint_as_float(u2.y & 0xFFFF0000u), v3);
            v0 = fmaf(fw11, __uint_as_float(u3.x << 16), v0);
            v1 = fmaf(fw11, __uint_as_float(u3.x & 0xFFFF0000u), v1);
            v2 = fmaf(fw11, __uint_as_float(u3.y << 16), v2);
            v3 = fmaf(fw11, __uint_as_float(u3.y & 0xFFFF0000u), v3);
            uint2 pk;
            pk.x = (f32_to_bf16_rne(v1) << 16) | f32_to_bf16_rne(v0);
            pk.y = (f32_to_bf16_rne(v3) << 16) | f32_to_bf16_rne(v2);
            *(uint2*)(MW + (l & 15) * 400 + (l >> 4) * 128 + m16 * 8) = pk;
        }
    };

    auto phaseC = [&](int kc) {
        const unsigned short* wkc = wt + kc * (6 * 4 * 512);
#pragma unroll
        for (int ks = 0; ks < 6; ++ks) {
            const bf16x8 bfrag =
                *(const bf16x8*)(MW + m16 * 400 + ks * 64 + quad * 16);
#pragma unroll
            for (int ot = 0; ot < 4; ++ot) {
                const bf16x8 afrag =
                    *(const bf16x8*)(wkc + (ks * 4 + ot) * 512 + lane * 8);
                acc[ot] = __builtin_amdgcn_mfma_f32_16x16x32_bf16(afrag, bfrag,
                                                                  acc[ot], 0, 0, 0);
            }
        }
    };

    bload(0);
    __builtin_amdgcn_sched_barrier(0);   // keep all 48 issued before use
    for (int kc = 0; kc < 3; ++kc) {
        bfinish(kc);
        if (kc < 2) {
            bload(kc + 1);
            __builtin_amdgcn_sched_barrier(0);
        }
        phaseC(kc);
    }

    float* ob = out + b * (COUT * HW) + row * 64 + qbase + m16;
#pragma unroll
    for (int ot = 0; ot < 4; ++ot)
#pragma unroll
        for (int r = 0; r < 4; ++r) {
            const int o = ot * 16 + quad * 4 + r;
            ob[o * HW] = acc[ot][r] + bias[o];
        }
}

extern "C" void kernel_launch(void* const* d_in, const int* in_sizes, int n_in,
                              void* d_out, int out_size, void* d_ws,
                              size_t ws_size, hipStream_t stream) {
    const float* x    = (const float*)d_in[0];
    const float* off  = (const float*)d_in[1];
    const float* mask = (const float*)d_in[2];
    const float* w    = (const float*)d_in[3];
    const float* bias = (const float*)d_in[4];
    float* out = (float*)d_out;

    unsigned short* xt = (unsigned short*)d_ws;                     // 8388608 B
    unsigned short* wt = (unsigned short*)((char*)d_ws + 8388608);  // 73728 B

    prep_kernel<<<1024 + 144, 256, 0, stream>>>(x, w, xt, wt);
    dcn_main_kernel<<<2048, 128, 0, stream>>>(off, mask, xt, wt, bias, out);
}

// Round 10
// 113.659 us; speedup vs baseline: 1.0580x; 1.0580x over previous
//
#include <hip/hip_runtime.h>

#define BATCH 16
#define C_IN  64
#define HH    64
#define WW    64
#define COUT  64
#define KK    9
#define HW    4096
#define CK    576
#define MROWB 400   // Mlds row stride bytes: 384 data + 16 pad (25 x 16B, odd -> even bank spread)

typedef __bf16 bf16x8 __attribute__((ext_vector_type(8)));
typedef float  f32x16 __attribute__((ext_vector_type(16)));
typedef unsigned int u32x2 __attribute__((ext_vector_type(2)));

__device__ __forceinline__ unsigned int f32_to_bf16_rne(float f) {
    unsigned int b = __float_as_uint(f);
    b += 0x7FFFu + ((b >> 16) & 1u);
    return b >> 16;  // low 16 bits valid
}

// Fused prep.  Blocks 0..1023: x (B,C,H,W) f32 -> xt (B,H,W,C) bf16.
// Blocks 1024..1167: w (Cout,C,3,3) f32 -> wt2 in 32x32x16 A-fragment order:
//   wt2[(((kc*12+ks)*2+ot)*64 + lane)*8 + j] = W[o=ot*32+(lane&31)]
//       [k_local=ks*16+(lane>>5)*8+j]   (k_local=tap*64+c within chunk kc)
// so each afrag load is 64 lanes x 16 B contiguous (1 KB, wave-uniform).
__global__ __launch_bounds__(256) void prep_kernel(
    const float* __restrict__ x, const float* __restrict__ w,
    unsigned short* __restrict__ xt, unsigned short* __restrict__ wt2) {
    __shared__ unsigned short tile[64][72];
    const int t = threadIdx.x;
    const int blk = blockIdx.x;
    if (blk < 1024) {
        const int b = blk >> 6, y = blk & 63;
        const float* xrow = x + ((b * 64) * 64 + y) * 64;
#pragma unroll
        for (int it = 0; it < 4; ++it) {
            const int idx = it * 256 + t;
            const int c = idx >> 4, seg = idx & 15;
            const float4 v = *(const float4*)(xrow + c * HW + seg * 4);
            tile[seg * 4 + 0][c] = (unsigned short)f32_to_bf16_rne(v.x);
            tile[seg * 4 + 1][c] = (unsigned short)f32_to_bf16_rne(v.y);
            tile[seg * 4 + 2][c] = (unsigned short)f32_to_bf16_rne(v.z);
            tile[seg * 4 + 3][c] = (unsigned short)f32_to_bf16_rne(v.w);
        }
        __syncthreads();
#pragma unroll
        for (int it = 0; it < 2; ++it) {
            const int idx = it * 256 + t;
            const int xx = idx >> 3, cs = idx & 7;
            *(int4*)&xt[((b * HW) + y * 64 + xx) * 64 + cs * 8] =
                *(const int4*)&tile[xx][cs * 8];
        }
    } else {
        const int i = (blk - 1024) * 256 + t;  // 0..36863
        const int j = i & 7;
        const int l = (i >> 3) & 63;
        const int ot = (i >> 9) & 1;
        const int r = i >> 10;           // 0..35
        const int ks = r % 12, kc = r / 12;
        const int o  = ot * 32 + (l & 31);
        const int kl = ks * 16 + (l >> 5) * 8 + j;   // 0..191
        const int tap = kl >> 6, c = kl & 63;
        const int k = kc * 3 + tap;
        wt2[i] = (unsigned short)f32_to_bf16_rne(w[o * CK + c * KK + k]);
    }
}

// Main.  Block = 128 thr = 2 waves = one image row; wave owns 32 px x all
// 64 cout via 32x32x16 MFMA (2 o-tiles).  R10 theory: TCP line-touch bound;
// halving wave count (n=16 -> n=32 px/wave) halves the wt afrag line
// traffic (each wave reads all 72 KB of weights once).  Wave-private LDS,
// no __syncthreads.  Per chunk (3 taps, K=192): gathers in 2 halves of 48
// (quarter-wave dwordx2 per corner), unpack -> Mlds, then 12 K-steps x 2
// o-tiles of v_mfma_f32_32x32x16_bf16 with 1-KB contiguous afrag loads.
// Retained: XCD image pinning (R2), CU row-clustering (R7), prologue
// params (R7).  Dropped: NT on gathers (neutral in R9), sched_barriers.
__global__ __launch_bounds__(128, 2) void dcn_main_kernel(
    const float* __restrict__ offset, const float* __restrict__ mask,
    const unsigned short* __restrict__ xt, const unsigned short* __restrict__ wt2,
    const float* __restrict__ bias, float* __restrict__ out) {
    __shared__ __align__(16) unsigned short Mlds[2][32 * (MROWB / 2)];  // 2 x 12800 B
    __shared__ __align__(16) int PWw[2][288 * 4];                       // 2 x 4608 B
    __shared__ __align__(8) unsigned short PWa[2][288 * 4];             // 2 x 2304 B

    const int t    = threadIdx.x;
    const int wave = __builtin_amdgcn_readfirstlane(t >> 6);
    const int lane = t & 63;
    const int quad = lane >> 4, m16 = lane & 15;
    const int n32  = lane & 31, half = lane >> 5;

    const int blk = blockIdx.x;
    const int xcd = blk & 7;                    // 2 images per XCD (R2)
    const int i8  = blk >> 3;                   // 0..127 within XCD
    const int s   = ((i8 & 31) << 2) | (i8 >> 5);  // 4 adjacent rows per CU (R7)
    const int b   = (xcd << 1) | (s >> 6);
    const int row = s & 63;
    const int qb  = wave * 32;                  // this wave's 32-px strip

    f32x16 acc[2];
#pragma unroll
    for (int ot = 0; ot < 2; ++ot)
#pragma unroll
        for (int r = 0; r < 16; ++r) acc[ot][r] = 0.f;

    const float* offb = offset + b * (2 * KK * HW) + row * 64;
    const float* mb   = mask + b * (KK * HW) + row * 64;
    const char* xtb   = (const char*)(xt + b * (HW * 64));
    char* MW = (char*)Mlds[wave];
    const int co = m16 * 8;          // channel byte offset within a pixel

    // ---- Prologue: params for all 9 taps x 32 px (288 items) ----
#pragma unroll
    for (int it = 0; it < 5; ++it) {
        const int item = it * 64 + lane;        // tap*32 + pxi
        if (item < 288) {
            const int tap = item >> 5;
            const int pxi = item & 31;
            const int ky = tap / 3, kx = tap - ky * 3;
            const int q = qb + pxi;
            const float oy = __builtin_nontemporal_load(&offb[(2 * tap) * HW + q]);
            const float ox = __builtin_nontemporal_load(&offb[(2 * tap + 1) * HW + q]);
            const float mk = __builtin_nontemporal_load(&mb[tap * HW + q]);
            const float py  = oy + (float)(row - 1 + ky);
            const float pxf = ox + (float)(q - 1 + kx);
            const float y0f = floorf(py), x0f = floorf(pxf);
            const float wy = py - y0f, wx = pxf - x0f;
            const int y0 = (int)y0f, x0 = (int)x0f;
            const int y1 = y0 + 1,   x1 = x0 + 1;
            const float vy0 = (y0 >= 0 && y0 < HH) ? 1.f : 0.f;
            const float vy1 = (y1 >= 0 && y1 < HH) ? 1.f : 0.f;
            const float vx0 = (x0 >= 0 && x0 < WW) ? 1.f : 0.f;
            const float vx1 = (x1 >= 0 && x1 < WW) ? 1.f : 0.f;
            const float w00 = (1.f - wy) * (1.f - wx) * vy0 * vx0 * mk;
            const float w01 = (1.f - wy) * wx         * vy0 * vx1 * mk;
            const float w10 = wy * (1.f - wx)         * vy1 * vx0 * mk;
            const float w11 = wy * wx                 * vy1 * vx1 * mk;
            const int cy0 = min(max(y0, 0), HH - 1), cy1 = min(max(y1, 0), HH - 1);
            const int cx0 = min(max(x0, 0), WW - 1), cx1 = min(max(x1, 0), WW - 1);
            int4 P0;
            P0.x = __float_as_int(w00); P0.y = __float_as_int(w01);
            P0.z = __float_as_int(w10); P0.w = __float_as_int(w11);
            *(int4*)&PWw[wave][item * 4] = P0;
            ushort4 A;
            A.x = (unsigned short)(cy0 * 64 + cx0);
            A.y = (unsigned short)(cy0 * 64 + cx1);
            A.z = (unsigned short)(cy1 * 64 + cx0);
            A.w = (unsigned short)(cy1 * 64 + cx1);
            *(ushort4*)&PWa[wave][item * 4] = A;
        }
    }

    u32x2 g[12][4];                  // 48 in-flight gathers (96 VGPR)

    // h: half of chunk (items h*48 .. h*48+47 of the chunk's 96)
    auto bload = [&](int kc, int h) {
        const unsigned short* Pa = &PWa[wave][0] + (kc * 96 + h * 48) * 4;
#pragma unroll
        for (int i = 0; i < 12; ++i) {
            const int l = i * 4 + quad;
            const ushort4 a = *(const ushort4*)(Pa + l * 4);
            g[i][0] = *(const u32x2*)(xtb + ((int)a.x << 7) + co);
            g[i][1] = *(const u32x2*)(xtb + ((int)a.y << 7) + co);
            g[i][2] = *(const u32x2*)(xtb + ((int)a.z << 7) + co);
            g[i][3] = *(const u32x2*)(xtb + ((int)a.w << 7) + co);
        }
    };

    auto bfinish = [&](int kc, int h) {
        const int* Pw = &PWw[wave][0] + (kc * 96 + h * 48) * 4;
#pragma unroll
        for (int i = 0; i < 12; ++i) {
            const int l = i * 4 + quad;
            const int item = h * 48 + l;         // within-chunk item
            const int4 p0 = *(const int4*)(Pw + l * 4);
            const float fw00 = __int_as_float(p0.x), fw01 = __int_as_float(p0.y);
            const float fw10 = __int_as_float(p0.z), fw11 = __int_as_float(p0.w);
            const u32x2 u0 = g[i][0], u1 = g[i][1], u2 = g[i][2], u3 = g[i][3];
            float v0, v1, v2, v3;
            v0 = fw00 * __uint_as_float(u0.x << 16);
            v1 = fw00 * __uint_as_float(u0.x & 0xFFFF0000u);
            v2 = fw00 * __uint_as_float(u0.y << 16);
            v3 = fw00 * __uint_as_float(u0.y & 0xFFFF0000u);
            v0 = fmaf(fw01, __uint_as_float(u1.x << 16), v0);
            v1 = fmaf(fw01, __uint_as_float(u1.x & 0xFFFF0000u), v1);
            v2 = fmaf(fw01, __uint_as_float(u1.y << 16), v2);
            v3 = fmaf(fw01, __uint_as_float(u1.y & 0xFFFF0000u), v3);
            v0 = fmaf(fw10, __uint_as_float(u2.x << 16), v0);
            v1 = fmaf(fw10, __uint_as_float(u2.x & 0xFFFF0000u), v1);
            v2 = fmaf(fw10, __uint_as_float(u2.y << 16), v2);
            v3 = fmaf(fw10, __uint_as_float(u2.y & 0xFFFF0000u), v3);
            v0 = fmaf(fw11, __uint_as_float(u3.x << 16), v0);
            v1 = fmaf(fw11, __uint_as_float(u3.x & 0xFFFF0000u), v1);
            v2 = fmaf(fw11, __uint_as_float(u3.y << 16), v2);
            v3 = fmaf(fw11, __uint_as_float(u3.y & 0xFFFF0000u), v3);
            uint2 pk;
            pk.x = (f32_to_bf16_rne(v1) << 16) | f32_to_bf16_rne(v0);
            pk.y = (f32_to_bf16_rne(v3) << 16) | f32_to_bf16_rne(v2);
            // Mlds[pxi][tap*64ch]: row = item&31, col block = (item>>5)*128 B
            *(uint2*)(MW + (item & 31) * MROWB + (item >> 5) * 128 + m16 * 8) = pk;
        }
    };

    auto phaseC = [&](int kc) {
#pragma unroll
        for (int ks = 0; ks < 12; ++ks) {
            const bf16x8 bfrag =
                *(const bf16x8*)(MW + n32 * MROWB + ks * 32 + half * 16);
#pragma unroll
            for (int ot = 0; ot < 2; ++ot) {
                const bf16x8 afrag = *(const bf16x8*)(
                    wt2 + (((kc * 12 + ks) * 2 + ot) << 9) + lane * 8);
                acc[ot] = __builtin_amdgcn_mfma_f32_32x32x16_bf16(afrag, bfrag,
                                                                  acc[ot], 0, 0, 0);
            }
        }
    };

    for (int kc = 0; kc < 3; ++kc) {
        bload(kc, 0);
        bfinish(kc, 0);   // compiler emits partial vmcnt waits (issue order)
        bload(kc, 1);
        bfinish(kc, 1);
        phaseC(kc);
    }

    // ---- Epilogue: 32x32 C/D: col=lane&31 (px), row=(r&3)+8*(r>>2)+4*half ----
    float* ob = out + b * (COUT * HW) + row * 64 + qb + n32;
#pragma unroll
    for (int ot = 0; ot < 2; ++ot)
#pragma unroll
        for (int r = 0; r < 16; ++r) {
            const int o = ot * 32 + (r & 3) + 8 * (r >> 2) + 4 * half;
            ob[o * HW] = acc[ot][r] + bias[o];
        }
}

extern "C" void kernel_launch(void* const* d_in, const int* in_sizes, int n_in,
                              void* d_out, int out_size, void* d_ws,
                              size_t ws_size, hipStream_t stream) {
    const float* x    = (const float*)d_in[0];
    const float* off  = (const float*)d_in[1];
    const float* mask = (const float*)d_in[2];
    const float* w    = (const float*)d_in[3];
    const float* bias = (const float*)d_in[4];
    float* out = (float*)d_out;

    unsigned short* xt  = (unsigned short*)d_ws;                     // 8388608 B
    unsigned short* wt2 = (unsigned short*)((char*)d_ws + 8388608);  // 73728 B

    prep_kernel<<<1024 + 144, 256, 0, stream>>>(x, w, xt, wt2);
    dcn_main_kernel<<<1024, 128, 0, stream>>>(off, mask, xt, wt2, bias, out);
}